// Round 1
// baseline (39.345 us; speedup 1.0000x reference)
//
#include <hip/hip_runtime.h>

// Separable factorization of the 3x3 window:
//   w = outer(v, v), v = [A_W, B_W, A_W]
//   A_W^2 = 0.09474166, B_W^2 = 0.14776132, A_W*B_W = 0.11831801
#define A_W 0.30780133f
#define B_W 0.38439735f

#define IMG_H 512
#define IMG_W 512
#define CROP_LO 5
#define CROP_HI 507          // exclusive: rows/cols 5..506 are kept (502 each)
#define STRIP_ROWS 32
#define BLOCK_THREADS 256

// Horizontal separable pass for one row: 5 weighted sums at column j.
__device__ __forceinline__ void hrow(const float* __restrict__ Xr,
                                     const float* __restrict__ Yr, int j,
                                     float& s1, float& s2, float& s11,
                                     float& s22, float& s12) {
    float xl = Xr[j - 1], xc = Xr[j], xr = Xr[j + 1];
    float yl = Yr[j - 1], yc = Yr[j], yr = Yr[j + 1];
    s1  = A_W * (xl + xr)           + B_W * xc;
    s2  = A_W * (yl + yr)           + B_W * yc;
    s11 = A_W * (xl * xl + xr * xr) + B_W * (xc * xc);
    s22 = A_W * (yl * yl + yr * yr) + B_W * (yc * yc);
    s12 = A_W * (xl * yl + xr * yr) + B_W * (xc * yc);
}

__global__ __launch_bounds__(BLOCK_THREADS) void ssim_loss_main(
    const float* __restrict__ X, const float* __restrict__ Y,
    float* __restrict__ partials) {
    const int tid = threadIdx.x;
    const int b   = blockIdx.z;
    const int j   = CROP_LO + blockIdx.x * BLOCK_THREADS + tid;
    const int i0  = CROP_LO + blockIdx.y * STRIP_ROWS;
    const int rows = min(STRIP_ROWS, CROP_HI - i0);

    const float* Xb = X + (size_t)b * IMG_H * IMG_W;
    const float* Yb = Y + (size_t)b * IMG_H * IMG_W;

    float acc = 0.0f;
    if (j < CROP_HI) {
        // Sliding 3-row window of horizontal sums: prev, curr, next.
        float p1, p2, p11, p22, p12;
        float c1, c2, c11, c22, c12;
        hrow(Xb + (size_t)(i0 - 1) * IMG_W, Yb + (size_t)(i0 - 1) * IMG_W, j,
             p1, p2, p11, p22, p12);
        hrow(Xb + (size_t)i0 * IMG_W, Yb + (size_t)i0 * IMG_W, j,
             c1, c2, c11, c22, c12);

        for (int r = 0; r < rows; ++r) {
            const int inext = i0 + r + 1;
            float n1, n2, n11, n22, n12;
            hrow(Xb + (size_t)inext * IMG_W, Yb + (size_t)inext * IMG_W, j,
                 n1, n2, n11, n22, n12);

            // Vertical separable combine.
            float s1  = A_W * (p1  + n1)  + B_W * c1;
            float s2  = A_W * (p2  + n2)  + B_W * c2;
            float s11 = A_W * (p11 + n11) + B_W * c11;
            float s22 = A_W * (p22 + n22) + B_W * c22;
            float s12 = A_W * (p12 + n12) + B_W * c12;

            float v1 = s11 - s1 * s1;     // sigma1_sq
            float v2 = s22 - s2 * s2;     // sigma2_sq
            float cv = s12 - s1 * s2;     // sigma12
            acc += v1 * v2 - 2.0f * cv;

            // rotate window
            p1 = c1; p2 = c2; p11 = c11; p22 = c22; p12 = c12;
            c1 = n1; c2 = n2; c11 = n11; c22 = n22; c12 = n12;
        }
    }

    // Block reduction: wave64 shuffle, then LDS across 4 waves.
    for (int off = 32; off > 0; off >>= 1) acc += __shfl_down(acc, off, 64);
    __shared__ float wsum[BLOCK_THREADS / 64];
    const int wave = tid >> 6, lane = tid & 63;
    if (lane == 0) wsum[wave] = acc;
    __syncthreads();
    if (tid == 0) {
        float s = wsum[0] + wsum[1] + wsum[2] + wsum[3];
        partials[blockIdx.x + gridDim.x * (blockIdx.y + gridDim.y * blockIdx.z)] = s;
    }
}

__global__ __launch_bounds__(BLOCK_THREADS) void ssim_loss_finalize(
    const float* __restrict__ partials, int n, float* __restrict__ out) {
    const int tid = threadIdx.x;
    float s = 0.0f;
    for (int i = tid; i < n; i += BLOCK_THREADS) s += partials[i];
    for (int off = 32; off > 0; off >>= 1) s += __shfl_down(s, off, 64);
    __shared__ float wsum[BLOCK_THREADS / 64];
    if ((tid & 63) == 0) wsum[tid >> 6] = s;
    __syncthreads();
    if (tid == 0) {
        float total = wsum[0] + wsum[1] + wsum[2] + wsum[3];
        out[0] = total * (1.0f / 252004.0f);   // mean over 502*502, summed over batch
    }
}

extern "C" void kernel_launch(void* const* d_in, const int* in_sizes, int n_in,
                              void* d_out, int out_size, void* d_ws, size_t ws_size,
                              hipStream_t stream) {
    const float* X = (const float*)d_in[0];
    const float* Y = (const float*)d_in[1];
    float* out = (float*)d_out;
    float* partials = (float*)d_ws;   // 2048 floats

    // Columns 5..506 covered by 2 blocks of 256 threads; rows by 16 strips of 32.
    dim3 grid(2, 16, 64);
    ssim_loss_main<<<grid, BLOCK_THREADS, 0, stream>>>(X, Y, partials);
    ssim_loss_finalize<<<1, BLOCK_THREADS, 0, stream>>>(partials, 2048, out);
}